// Round 15
// baseline (124.372 us; speedup 1.0000x reference)
//
#include <hip/hip_runtime.h>

typedef _Float16 half8  __attribute__((ext_vector_type(8)));
typedef _Float16 half4v __attribute__((ext_vector_type(4)));
typedef _Float16 half2v __attribute__((ext_vector_type(2)));
typedef float    f32x4  __attribute__((ext_vector_type(4)));

#define N_VOX  262144
#define BATCH  4
#define NBOX   32
#define C3D_   64
#define C2D_   256
#define MIDC   128
#define OUTC   64
#define IH     96
#define IW     312
#define IHW    (IH*IW)          // 29952
#define EPSF   1e-5f

#define MFMA16(a,b,c) __builtin_amdgcn_mfma_f32_16x16x32_f16(a,b,c,0,0,0)

// ---------------------------------------------------------------------------
// prep_all: (a) BN-folded fp16 weights + fp32 biases, (b) per-voxel w3d.
// (identical to round 8)
// ---------------------------------------------------------------------------
__global__ __launch_bounds__(256) void prep_all(
    const int*   __restrict__ coords,  // [N][4]
    const float* __restrict__ gtb,     // [B][32][7]
    const int*   __restrict__ gtc,     // [B][32]
    const float* __restrict__ w_vt, const float* __restrict__ g_vt,
    const float* __restrict__ v_vt, const float* __restrict__ b_vt,
    const float* __restrict__ be_vt, const float* __restrict__ m_vt,
    const float* __restrict__ w_it, const float* __restrict__ g_it,
    const float* __restrict__ v_it, const float* __restrict__ b_it,
    const float* __restrict__ be_it, const float* __restrict__ m_it,
    const float* __restrict__ w_f, const float* __restrict__ g_f,
    const float* __restrict__ v_f, const float* __restrict__ b_f,
    const float* __restrict__ be_f, const float* __restrict__ m_f,
    _Float16* __restrict__ w_vt_s, _Float16* __restrict__ w_it_s,
    _Float16* __restrict__ w_f1_s, _Float16* __restrict__ w_f2_s,
    float* __restrict__ sb_vt, float* __restrict__ sb_it,
    float* __restrict__ sb_f,  float* __restrict__ w3d_buf)
{
    __shared__ float s_box[BATCH*NBOX*7];
    __shared__ int   s_cls[BATCH*NBOX];
    const int tid = threadIdx.x;
    for (int i = tid; i < BATCH*NBOX*7; i += 256) s_box[i] = gtb[i];
    for (int i = tid; i < BATCH*NBOX;   i += 256) s_cls[i] = gtc[i];
    __syncthreads();

    const int v = blockIdx.x * 256 + tid;

    {
        const int4 cc = ((const int4*)coords)[v];
        const int vb = cc.x;
        const float crx = cc.w * 0.05f;
        const float cry = cc.z * 0.05f - 40.0f;
        const float crz = cc.y * 0.1f  - 3.0f;
        const float* gb = s_box + vb*(NBOX*7);
        int lastm = -1;
        #pragma unroll 8
        for (int m = 0; m < NBOX; ++m) {
            float dx = gb[m*7+3];
            bool in = (fabsf(crx - gb[m*7+0]) < dx * 0.5f) &&
                      (fabsf(cry - gb[m*7+1]) < gb[m*7+4] * 0.5f) &&
                      (fabsf(crz - gb[m*7+2]) < gb[m*7+5] * 0.5f) &&
                      (dx > 0.f);
            if (in) lastm = m;
        }
        float w3 = 0.8f;
        if (lastm >= 0) {
            int cls = s_cls[vb*NBOX + lastm];
            w3 = (cls == 0) ? 0.85f : ((cls == 1) ? 0.95f : 0.6f);
        }
        w3d_buf[v] = w3;
    }

    if (v < MIDC*C3D_) {
        int o = v >> 6;
        float sa = g_vt[o] * rsqrtf(v_vt[o] + EPSF);
        w_vt_s[v] = (_Float16)(w_vt[v] * sa);
    }
    if (v < MIDC*C2D_) {
        int o = v >> 8;
        float sa = g_it[o] * rsqrtf(v_it[o] + EPSF);
        w_it_s[v] = (_Float16)(w_it[v] * sa);
    }
    if (v < OUTC*C2D_) {
        int o = v >> 8, k = v & 255;
        float sa = g_f[o] * rsqrtf(v_f[o] + EPSF);
        float val = w_f[v] * sa;
        if (k < 128) w_f1_s[o*128 + k]       = (_Float16)val;
        else         w_f2_s[o*128 + (k-128)] = (_Float16)val;
    }
    if (v < MIDC) {
        float sa = g_vt[v] * rsqrtf(v_vt[v] + EPSF);
        sb_vt[v] = (b_vt[v] - m_vt[v]) * sa + be_vt[v];
        float si = g_it[v] * rsqrtf(v_it[v] + EPSF);
        sb_it[v] = (b_it[v] - m_it[v]) * si + be_it[v];
    }
    if (v < OUTC) {
        float sa = g_f[v] * rsqrtf(v_f[v] + EPSF);
        sb_f[v] = (b_f[v] - m_f[v]) * sa + be_f[v];
    }
}

// ---------------------------------------------------------------------------
// Kernel A: T = relu(img @ w_it_s^T + sb_it), J = T @ w_f2_s^T
// -> J[b][p][64] fp16.  (identical to round 8)
// ---------------------------------------------------------------------------
__global__ __launch_bounds__(256, 4) void img_transform(
    const float* __restrict__ img,        // [B][256][H*W]
    const _Float16* __restrict__ w_it_s,  // [128][256] fp16, BN-folded
    const _Float16* __restrict__ w_f2_s,  // [64][128] fp16, BN-folded
    const float* __restrict__ sb_it,      // [128]
    _Float16* __restrict__ Jout)          // [B][H*W][64] fp16
{
    __shared__ __align__(16) _Float16 s_mem[64*136];

    const int p0   = blockIdx.x * 64;
    const int b    = blockIdx.y;
    const int tid  = threadIdx.x;
    const int lane = tid & 63;
    const int wv   = tid >> 6;
    const int r    = lane & 15;
    const int kh   = lane >> 4;

    f32x4 acc[4][2] = {};

    const int p  = tid & 63;
    const int cb = (tid >> 6) * 2;

    const float sbit0 = sb_it[wv*32 + r];
    const float sbit1 = sb_it[wv*32 + 16 + r];

    for (int kc = 0; kc < 4; ++kc) {
        #pragma unroll
        for (int i = 0; i < 8; ++i) {
            int c = cb + i*8;
            float x0 = img[(size_t)(b*C2D_ + kc*64 + c    )*IHW + p0 + p];
            float x1 = img[(size_t)(b*C2D_ + kc*64 + c + 1)*IHW + p0 + p];
            half2v h; h[0] = (_Float16)x0; h[1] = (_Float16)x1;
            *(half2v*)&s_mem[p*72 + c] = h;
        }
        half8 bw[2][2];
        #pragma unroll
        for (int nt = 0; nt < 2; ++nt)
            #pragma unroll
            for (int ks = 0; ks < 2; ++ks) {
                int o = wv*32 + nt*16 + r;
                bw[nt][ks] = *(const half8*)&w_it_s[o*C2D_ + kc*64 + ks*32 + kh*8];
            }
        __syncthreads();
        #pragma unroll
        for (int mt = 0; mt < 4; ++mt)
            #pragma unroll
            for (int ks = 0; ks < 2; ++ks) {
                half8 af = *(const half8*)&s_mem[(mt*16 + r)*72 + ks*32 + kh*8];
                acc[mt][0] = MFMA16(af, bw[0][ks], acc[mt][0]);
                acc[mt][1] = MFMA16(af, bw[1][ks], acc[mt][1]);
            }
        __syncthreads();
    }

    #pragma unroll
    for (int nt = 0; nt < 2; ++nt) {
        int o = wv*32 + nt*16 + r;
        float sb = nt ? sbit1 : sbit0;
        #pragma unroll
        for (int mt = 0; mt < 4; ++mt)
            #pragma unroll
            for (int rr = 0; rr < 4; ++rr) {
                int p2 = mt*16 + kh*4 + rr;
                s_mem[p2*136 + o] = (_Float16)fmaxf(acc[mt][nt][rr] + sb, 0.f);
            }
    }
    __syncthreads();

    {
        const int o2 = wv*16 + r;
        half8 bf2[4];
        #pragma unroll
        for (int ks = 0; ks < 4; ++ks)
            bf2[ks] = *(const half8*)&w_f2_s[o2*128 + ks*32 + kh*8];
        #pragma unroll
        for (int mt = 0; mt < 4; ++mt) {
            f32x4 a2 = {0.f,0.f,0.f,0.f};
            #pragma unroll
            for (int ks = 0; ks < 4; ++ks) {
                half8 af = *(const half8*)&s_mem[(mt*16 + r)*136 + ks*32 + kh*8];
                a2 = MFMA16(af, bf2[ks], a2);
            }
            #pragma unroll
            for (int rr = 0; rr < 4; ++rr) {
                int p2 = mt*16 + kh*4 + rr;
                Jout[(size_t)(b*IHW + p0 + p2)*OUTC + o2] = (_Float16)a2[rr];
            }
        }
    }
}

// ---------------------------------------------------------------------------
// Kernel B: ZERO-BARRIER wave-local tiling. Each wave owns 16 voxels
// end-to-end; all LDS deps are intra-wave (lgkmcnt ordering). A-fragments
// loaded directly from global vf. Math identical to round 8.
// ---------------------------------------------------------------------------
__global__ __launch_bounds__(256, 3) void voxel_fuse(
    const float* __restrict__ vf,         // [N][64]
    const int*   __restrict__ coords,     // [N][4]
    const _Float16* __restrict__ w_vt_s,  // [128][64] BN-folded
    const float* __restrict__ sb_vt,      // [128]
    const _Float16* __restrict__ Jimg,    // [B][H*W][64]
    const _Float16* __restrict__ w_f1_s,  // [64][128] BN-folded
    const float* __restrict__ sb_f,       // [64]
    const float* __restrict__ w3d_buf,    // [N]
    float* __restrict__ out)              // [N][64]
{
    __shared__ __align__(16) _Float16 s_fused[4][16*136];  // per-wave
    __shared__ __align__(16) _Float16 s_j[4][16*72];       // per-wave

    const int tid  = threadIdx.x;
    const int w    = tid >> 6;
    const int lane = tid & 63;
    const int r    = lane & 15;
    const int kh   = lane >> 4;
    const int vj   = lane >> 2;     // gather voxel within wave tile
    const int q_   = lane & 3;
    const int vb0  = blockIdx.x * 64 + w * 16;   // wave's first voxel

    _Float16* fused = s_fused[w];
    _Float16* sj    = s_j[w];

    // ---- issue vf fragment loads: row vb0+r, fp32 ----
    const float4* vfrow = (const float4*)(vf + (size_t)(vb0 + r)*C3D_);
    float4 xa0 = vfrow[kh*2];
    float4 xb0 = vfrow[kh*2 + 1];
    float4 xa1 = vfrow[8 + kh*2];
    float4 xb1 = vfrow[8 + kh*2 + 1];

    // ---- coords + per-lane gather meta (voxel vb0+vj, redundant x4) ----
    const int4 cc = ((const int4*)coords)[vb0 + vj];
    int ga[4]; float gw[4];
    {
        const int vb = cc.x;
        const float crx = cc.w * 0.05f;
        const float cry = cc.z * 0.05f - 40.0f;
        const float px = (crx + 0.025f) * 10.f + 156.f;
        const float py = (cry + 0.025f) * 10.f + 48.f;
        const float nx = fminf(fmaxf(px / 312.f * 2.f - 1.f, -1.f), 1.f);
        const float ny = fminf(fmaxf(py / 96.f  * 2.f - 1.f, -1.f), 1.f);
        const float fx = ((nx + 1.f) * 312.f - 1.f) * 0.5f;
        const float fy = ((ny + 1.f) * 96.f  - 1.f) * 0.5f;
        const float x0f = floorf(fx), y0f = floorf(fy);
        const float wx1 = fx - x0f, wy1 = fy - y0f;
        const int x0 = (int)x0f, y0 = (int)y0f;
        #pragma unroll
        for (int c = 0; c < 4; ++c) {
            int xi = x0 + (c & 1), yi = y0 + (c >> 1);
            bool valid = (xi >= 0) && (xi < IW) && (yi >= 0) && (yi < IH);
            int xc = min(max(xi, 0), IW - 1);
            int yc = min(max(yi, 0), IH - 1);
            ga[c] = ((vb*IH + yc)*IW + xc) * OUTC;
            float wx = (c & 1) ? wx1 : 1.f - wx1;
            float wy = (c >> 1) ? wy1 : 1.f - wy1;
            gw[c] = valid ? wx * wy : 0.f;
        }
    }

    // ---- issue J-gather loads early (consumed after phase 1) ----
    half8 jreg[4][2];
    #pragma unroll
    for (int c = 0; c < 4; ++c)
        #pragma unroll
        for (int h = 0; h < 2; ++h)
            jreg[c][h] = *(const half8*)&Jimg[ga[c] + (h*4 + q_)*8];

    // ---- w3d: epilogue rows (kh*4..+3) and own-gather voxel ----
    const float4 w3v = *(const float4*)&w3d_buf[vb0 + kh*4];
    const float invw = 1.f - w3d_buf[vb0 + vj];

    // ---- convert vf -> fp16 A-frags (row r, k = ks*32 + kh*8 + j) ----
    half8 af0, af1;
    af0[0]=(_Float16)xa0.x; af0[1]=(_Float16)xa0.y;
    af0[2]=(_Float16)xa0.z; af0[3]=(_Float16)xa0.w;
    af0[4]=(_Float16)xb0.x; af0[5]=(_Float16)xb0.y;
    af0[6]=(_Float16)xb0.z; af0[7]=(_Float16)xb0.w;
    af1[0]=(_Float16)xa1.x; af1[1]=(_Float16)xa1.y;
    af1[2]=(_Float16)xa1.z; af1[3]=(_Float16)xa1.w;
    af1[4]=(_Float16)xb1.x; af1[5]=(_Float16)xb1.y;
    af1[6]=(_Float16)xb1.z; af1[7]=(_Float16)xb1.w;

    // ---- phase 1: 16 voxels x 128 mid-channels, 8 o-tiles ----
    #pragma unroll
    for (int ot = 0; ot < 8; ++ot) {
        const int o = ot*16 + r;
        half8 b0 = *(const half8*)&w_vt_s[o*C3D_ + kh*8];
        half8 b1 = *(const half8*)&w_vt_s[o*C3D_ + 32 + kh*8];
        f32x4 a = {0.f,0.f,0.f,0.f};
        a = MFMA16(af0, b0, a);
        a = MFMA16(af1, b1, a);
        const float sb = sb_vt[o];
        #pragma unroll
        for (int rr = 0; rr < 4; ++rr) {
            int vloc = kh*4 + rr;
            fused[vloc*136 + ot*16 + r] =
                (_Float16)(fmaxf(a[rr] + sb, 0.f) * w3v[rr]);
        }
    }

    // ---- phase 1.5: gather combine -> sj (wave-local) ----
    #pragma unroll
    for (int h = 0; h < 2; ++h) {
        half8 res;
        #pragma unroll
        for (int i = 0; i < 8; ++i) {
            float s = gw[0]*(float)jreg[0][h][i] + gw[1]*(float)jreg[1][h][i]
                    + gw[2]*(float)jreg[2][h][i] + gw[3]*(float)jreg[3][h][i];
            res[i] = (_Float16)(s * invw);
        }
        *(half8*)&sj[vj*72 + (h*4 + q_)*8] = res;
    }

    // ---- phase 2: 16 voxels x 64 outs (A from wave-local LDS) ----
    half8 af2[4];
    #pragma unroll
    for (int ks = 0; ks < 4; ++ks)
        af2[ks] = *(const half8*)&fused[r*136 + ks*32 + kh*8];

    #pragma unroll
    for (int ot = 0; ot < 4; ++ot) {
        const int o = ot*16 + r;
        f32x4 a = {0.f,0.f,0.f,0.f};
        #pragma unroll
        for (int ks = 0; ks < 4; ++ks) {
            half8 b = *(const half8*)&w_f1_s[o*128 + ks*32 + kh*8];
            a = MFMA16(af2[ks], b, a);
        }
        const float sb = sb_f[o];
        #pragma unroll
        for (int rr = 0; rr < 4; ++rr) {
            int vloc = kh*4 + rr;
            float jv = (float)sj[vloc*72 + o];
            out[(size_t)(vb0 + vloc)*OUTC + o] = fmaxf(a[rr] + jv + sb, 0.f);
        }
    }
}

// ---------------------------------------------------------------------------
extern "C" void kernel_launch(void* const* d_in, const int* in_sizes, int n_in,
                              void* d_out, int out_size, void* d_ws, size_t ws_size,
                              hipStream_t stream)
{
    const float* vf    = (const float*)d_in[0];
    const int*   vc    = (const int*)  d_in[1];
    const float* img   = (const float*)d_in[2];
    const float* gtb   = (const float*)d_in[3];
    const int*   gtc   = (const int*)  d_in[4];
    const float* w_vt  = (const float*)d_in[5];
    const float* b_vt  = (const float*)d_in[6];
    const float* g_vt  = (const float*)d_in[7];
    const float* be_vt = (const float*)d_in[8];
    const float* m_vt  = (const float*)d_in[9];
    const float* v_vt  = (const float*)d_in[10];
    const float* w_it  = (const float*)d_in[11];
    const float* b_it  = (const float*)d_in[12];
    const float* g_it  = (const float*)d_in[13];
    const float* be_it = (const float*)d_in[14];
    const float* m_it  = (const float*)d_in[15];
    const float* v_it  = (const float*)d_in[16];
    const float* w_f   = (const float*)d_in[17];
    const float* b_f   = (const float*)d_in[18];
    const float* g_f   = (const float*)d_in[19];
    const float* be_f  = (const float*)d_in[20];
    const float* m_f   = (const float*)d_in[21];
    const float* v_f   = (const float*)d_in[22];

    _Float16* ws_h   = (_Float16*)d_ws;
    _Float16* Jbuf   = ws_h;                              // B*IHW*64 halves
    _Float16* w_vt_s = ws_h + (size_t)BATCH*IHW*OUTC;     // 8192
    _Float16* w_it_s = w_vt_s + MIDC*C3D_;                // 32768
    _Float16* w_f1_s = w_it_s + MIDC*C2D_;                // 8192
    _Float16* w_f2_s = w_f1_s + OUTC*128;                 // 8192
    float*    fbase  = (float*)(w_f2_s + OUTC*128);
    float* sb_vt   = fbase;                               // 128
    float* sb_it   = sb_vt + MIDC;                        // 128
    float* sb_f    = sb_it + MIDC;                        // 64
    float* w3d_buf = sb_f + OUTC;                         // N_VOX
    float* outp = (float*)d_out;

    prep_all<<<N_VOX/256, 256, 0, stream>>>(
        vc, gtb, gtc,
        w_vt, g_vt, v_vt, b_vt, be_vt, m_vt,
        w_it, g_it, v_it, b_it, be_it, m_it,
        w_f,  g_f,  v_f,  b_f,  be_f,  m_f,
        w_vt_s, w_it_s, w_f1_s, w_f2_s,
        sb_vt, sb_it, sb_f, w3d_buf);

    img_transform<<<dim3(IHW/64, BATCH), 256, 0, stream>>>(
        img, w_it_s, w_f2_s, sb_it, Jbuf);

    voxel_fuse<<<N_VOX/64, 256, 0, stream>>>(
        vf, vc, w_vt_s, sb_vt, Jbuf, w_f1_s, sb_f, w3d_buf, outp);
}

// Round 16
// 107.653 us; speedup vs baseline: 1.1553x; 1.1553x over previous
//
#include <hip/hip_runtime.h>

typedef _Float16 half8  __attribute__((ext_vector_type(8)));
typedef _Float16 half4v __attribute__((ext_vector_type(4)));
typedef _Float16 half2v __attribute__((ext_vector_type(2)));
typedef float    f32x4  __attribute__((ext_vector_type(4)));

#define N_VOX  262144
#define BATCH  4
#define NBOX   32
#define C3D_   64
#define C2D_   256
#define MIDC   128
#define OUTC   64
#define IH     96
#define IW     312
#define IHW    (IH*IW)          // 29952
#define EPSF   1e-5f

#define MFMA16(a,b,c) __builtin_amdgcn_mfma_f32_16x16x32_f16(a,b,c,0,0,0)

// ---------------------------------------------------------------------------
// prep_all: (a) BN-folded fp16 weights + fp32 biases, (b) per-voxel w3d.
// (identical to round 8)
// ---------------------------------------------------------------------------
__global__ __launch_bounds__(256) void prep_all(
    const int*   __restrict__ coords,  // [N][4]
    const float* __restrict__ gtb,     // [B][32][7]
    const int*   __restrict__ gtc,     // [B][32]
    const float* __restrict__ w_vt, const float* __restrict__ g_vt,
    const float* __restrict__ v_vt, const float* __restrict__ b_vt,
    const float* __restrict__ be_vt, const float* __restrict__ m_vt,
    const float* __restrict__ w_it, const float* __restrict__ g_it,
    const float* __restrict__ v_it, const float* __restrict__ b_it,
    const float* __restrict__ be_it, const float* __restrict__ m_it,
    const float* __restrict__ w_f, const float* __restrict__ g_f,
    const float* __restrict__ v_f, const float* __restrict__ b_f,
    const float* __restrict__ be_f, const float* __restrict__ m_f,
    _Float16* __restrict__ w_vt_s, _Float16* __restrict__ w_it_s,
    _Float16* __restrict__ w_f1_s, _Float16* __restrict__ w_f2_s,
    float* __restrict__ sb_vt, float* __restrict__ sb_it,
    float* __restrict__ sb_f,  float* __restrict__ w3d_buf)
{
    __shared__ float s_box[BATCH*NBOX*7];
    __shared__ int   s_cls[BATCH*NBOX];
    const int tid = threadIdx.x;
    for (int i = tid; i < BATCH*NBOX*7; i += 256) s_box[i] = gtb[i];
    for (int i = tid; i < BATCH*NBOX;   i += 256) s_cls[i] = gtc[i];
    __syncthreads();

    const int v = blockIdx.x * 256 + tid;

    {
        const int4 cc = ((const int4*)coords)[v];
        const int vb = cc.x;
        const float crx = cc.w * 0.05f;
        const float cry = cc.z * 0.05f - 40.0f;
        const float crz = cc.y * 0.1f  - 3.0f;
        const float* gb = s_box + vb*(NBOX*7);
        int lastm = -1;
        #pragma unroll 8
        for (int m = 0; m < NBOX; ++m) {
            float dx = gb[m*7+3];
            bool in = (fabsf(crx - gb[m*7+0]) < dx * 0.5f) &&
                      (fabsf(cry - gb[m*7+1]) < gb[m*7+4] * 0.5f) &&
                      (fabsf(crz - gb[m*7+2]) < gb[m*7+5] * 0.5f) &&
                      (dx > 0.f);
            if (in) lastm = m;
        }
        float w3 = 0.8f;
        if (lastm >= 0) {
            int cls = s_cls[vb*NBOX + lastm];
            w3 = (cls == 0) ? 0.85f : ((cls == 1) ? 0.95f : 0.6f);
        }
        w3d_buf[v] = w3;
    }

    if (v < MIDC*C3D_) {
        int o = v >> 6;
        float sa = g_vt[o] * rsqrtf(v_vt[o] + EPSF);
        w_vt_s[v] = (_Float16)(w_vt[v] * sa);
    }
    if (v < MIDC*C2D_) {
        int o = v >> 8;
        float sa = g_it[o] * rsqrtf(v_it[o] + EPSF);
        w_it_s[v] = (_Float16)(w_it[v] * sa);
    }
    if (v < OUTC*C2D_) {
        int o = v >> 8, k = v & 255;
        float sa = g_f[o] * rsqrtf(v_f[o] + EPSF);
        float val = w_f[v] * sa;
        if (k < 128) w_f1_s[o*128 + k]       = (_Float16)val;
        else         w_f2_s[o*128 + (k-128)] = (_Float16)val;
    }
    if (v < MIDC) {
        float sa = g_vt[v] * rsqrtf(v_vt[v] + EPSF);
        sb_vt[v] = (b_vt[v] - m_vt[v]) * sa + be_vt[v];
        float si = g_it[v] * rsqrtf(v_it[v] + EPSF);
        sb_it[v] = (b_it[v] - m_it[v]) * si + be_it[v];
    }
    if (v < OUTC) {
        float sa = g_f[v] * rsqrtf(v_f[v] + EPSF);
        sb_f[v] = (b_f[v] - m_f[v]) * sa + be_f[v];
    }
}

// ---------------------------------------------------------------------------
// Kernel A: T = relu(img @ w_it_s^T + sb_it), J = T @ w_f2_s^T
// -> J[b][p][64] fp16.  (identical to round 8)
// ---------------------------------------------------------------------------
__global__ __launch_bounds__(256, 4) void img_transform(
    const float* __restrict__ img,        // [B][256][H*W]
    const _Float16* __restrict__ w_it_s,  // [128][256] fp16, BN-folded
    const _Float16* __restrict__ w_f2_s,  // [64][128] fp16, BN-folded
    const float* __restrict__ sb_it,      // [128]
    _Float16* __restrict__ Jout)          // [B][H*W][64] fp16
{
    __shared__ __align__(16) _Float16 s_mem[64*136];

    const int p0   = blockIdx.x * 64;
    const int b    = blockIdx.y;
    const int tid  = threadIdx.x;
    const int lane = tid & 63;
    const int wv   = tid >> 6;
    const int r    = lane & 15;
    const int kh   = lane >> 4;

    f32x4 acc[4][2] = {};

    const int p  = tid & 63;
    const int cb = (tid >> 6) * 2;

    const float sbit0 = sb_it[wv*32 + r];
    const float sbit1 = sb_it[wv*32 + 16 + r];

    for (int kc = 0; kc < 4; ++kc) {
        #pragma unroll
        for (int i = 0; i < 8; ++i) {
            int c = cb + i*8;
            float x0 = img[(size_t)(b*C2D_ + kc*64 + c    )*IHW + p0 + p];
            float x1 = img[(size_t)(b*C2D_ + kc*64 + c + 1)*IHW + p0 + p];
            half2v h; h[0] = (_Float16)x0; h[1] = (_Float16)x1;
            *(half2v*)&s_mem[p*72 + c] = h;
        }
        half8 bw[2][2];
        #pragma unroll
        for (int nt = 0; nt < 2; ++nt)
            #pragma unroll
            for (int ks = 0; ks < 2; ++ks) {
                int o = wv*32 + nt*16 + r;
                bw[nt][ks] = *(const half8*)&w_it_s[o*C2D_ + kc*64 + ks*32 + kh*8];
            }
        __syncthreads();
        #pragma unroll
        for (int mt = 0; mt < 4; ++mt)
            #pragma unroll
            for (int ks = 0; ks < 2; ++ks) {
                half8 af = *(const half8*)&s_mem[(mt*16 + r)*72 + ks*32 + kh*8];
                acc[mt][0] = MFMA16(af, bw[0][ks], acc[mt][0]);
                acc[mt][1] = MFMA16(af, bw[1][ks], acc[mt][1]);
            }
        __syncthreads();
    }

    #pragma unroll
    for (int nt = 0; nt < 2; ++nt) {
        int o = wv*32 + nt*16 + r;
        float sb = nt ? sbit1 : sbit0;
        #pragma unroll
        for (int mt = 0; mt < 4; ++mt)
            #pragma unroll
            for (int rr = 0; rr < 4; ++rr) {
                int p2 = mt*16 + kh*4 + rr;
                s_mem[p2*136 + o] = (_Float16)fmaxf(acc[mt][nt][rr] + sb, 0.f);
            }
    }
    __syncthreads();

    {
        const int o2 = wv*16 + r;
        half8 bf2[4];
        #pragma unroll
        for (int ks = 0; ks < 4; ++ks)
            bf2[ks] = *(const half8*)&w_f2_s[o2*128 + ks*32 + kh*8];
        #pragma unroll
        for (int mt = 0; mt < 4; ++mt) {
            f32x4 a2 = {0.f,0.f,0.f,0.f};
            #pragma unroll
            for (int ks = 0; ks < 4; ++ks) {
                half8 af = *(const half8*)&s_mem[(mt*16 + r)*136 + ks*32 + kh*8];
                a2 = MFMA16(af, bf2[ks], a2);
            }
            #pragma unroll
            for (int rr = 0; rr < 4; ++rr) {
                int p2 = mt*16 + kh*4 + rr;
                Jout[(size_t)(b*IHW + p0 + p2)*OUTC + o2] = (_Float16)a2[rr];
            }
        }
    }
}

// ---------------------------------------------------------------------------
// Kernel B: R8 wave-split (o-channels across waves, weights in regs) with
// ONE delta: phase-1a A-fragments direct from global vf (drops s_vf + bar1);
// w3d via direct loads (drops s_w3d). ONE barrier total.
// ---------------------------------------------------------------------------
__global__ __launch_bounds__(256, 4) void voxel_fuse(
    const float* __restrict__ vf,         // [N][64]
    const int*   __restrict__ coords,     // [N][4]
    const _Float16* __restrict__ w_vt_s,  // [128][64] BN-folded
    const float* __restrict__ sb_vt,      // [128]
    const _Float16* __restrict__ Jimg,    // [B][H*W][64]
    const _Float16* __restrict__ w_f1_s,  // [64][128] BN-folded
    const float* __restrict__ sb_f,       // [64]
    const float* __restrict__ w3d_buf,    // [N]
    float* __restrict__ out)              // [N][64]
{
    __shared__ __align__(16) _Float16 s_fused[64*136];  // [v][o] pitch 136
    __shared__ __align__(16) _Float16 s_j[64*72];       // [v][o] pitch 72

    const int tid  = threadIdx.x;
    const int lane = tid & 63;
    const int wv   = tid >> 6;
    const int v0   = blockIdx.x * 64;
    const int r    = lane & 15;
    const int kh   = lane >> 4;
    const int vsv  = tid >> 2;
    const int q_   = tid & 3;

    // ---- coords + per-thread gather meta (voxel v0+vsv) ----
    const int4 cc = ((const int4*)coords)[v0 + vsv];
    int ga[4]; float gw[4];
    {
        const int vb = cc.x;
        const float crx = cc.w * 0.05f;
        const float cry = cc.z * 0.05f - 40.0f;
        const float px = (crx + 0.025f) * 10.f + 156.f;
        const float py = (cry + 0.025f) * 10.f + 48.f;
        const float nx = fminf(fmaxf(px / 312.f * 2.f - 1.f, -1.f), 1.f);
        const float ny = fminf(fmaxf(py / 96.f  * 2.f - 1.f, -1.f), 1.f);
        const float fx = ((nx + 1.f) * 312.f - 1.f) * 0.5f;
        const float fy = ((ny + 1.f) * 96.f  - 1.f) * 0.5f;
        const float x0f = floorf(fx), y0f = floorf(fy);
        const float wx1 = fx - x0f, wy1 = fy - y0f;
        const int x0 = (int)x0f, y0 = (int)y0f;
        #pragma unroll
        for (int c = 0; c < 4; ++c) {
            int xi = x0 + (c & 1), yi = y0 + (c >> 1);
            bool valid = (xi >= 0) && (xi < IW) && (yi >= 0) && (yi < IH);
            int xc = min(max(xi, 0), IW - 1);
            int yc = min(max(yi, 0), IH - 1);
            ga[c] = ((vb*IH + yc)*IW + xc) * OUTC;
            float wx = (c & 1) ? wx1 : 1.f - wx1;
            float wy = (c >> 1) ? wy1 : 1.f - wy1;
            gw[c] = valid ? wx * wy : 0.f;
        }
    }

    // ---- issue J-gather loads (L3; hide under A-loads + phase 1a) ----
    half8 jreg[4][2];
    #pragma unroll
    for (int c = 0; c < 4; ++c)
        #pragma unroll
        for (int h = 0; h < 2; ++h)
            jreg[c][h] = *(const half8*)&Jimg[ga[c] + (h*4 + q_)*8];

    // ---- w3d: epilogue rows + own-gather voxel (direct loads, L2-hot) ----
    float4 w3v[4];
    #pragma unroll
    for (int mt = 0; mt < 4; ++mt)
        w3v[mt] = *(const float4*)&w3d_buf[v0 + mt*16 + kh*4];
    const float invw = 1.f - w3d_buf[v0 + vsv];

    // ---- weight fragments + biases (L2-hot, register-resident) ----
    half8 bvt[2][2];
    float sbvt[2];
    #pragma unroll
    for (int nt = 0; nt < 2; ++nt) {
        int o = (2*wv + nt)*16 + r;
        #pragma unroll
        for (int ks = 0; ks < 2; ++ks)
            bvt[nt][ks] = *(const half8*)&w_vt_s[o*C3D_ + ks*32 + kh*8];
        sbvt[nt] = sb_vt[o];
    }
    const int of = wv*16 + r;
    half8 bf1[4];
    #pragma unroll
    for (int ks = 0; ks < 4; ++ks)
        bf1[ks] = *(const half8*)&w_f1_s[of*128 + ks*32 + kh*8];
    const float sbf = sb_f[of];

    // ---- phase 1a: A direct from global vf; vt=relu(..)*w3d -> s_fused ----
    const float4* vf4 = (const float4*)vf;   // 16 float4 per 64-ch row
    #pragma unroll
    for (int mt = 0; mt < 4; ++mt) {
        const size_t rowb = (size_t)(v0 + mt*16 + r) * 16 + kh*2;
        float4 xa = vf4[rowb];
        float4 xb = vf4[rowb + 1];
        float4 xc = vf4[rowb + 8];
        float4 xd = vf4[rowb + 9];
        half8 af0, af1;
        af0[0]=(_Float16)xa.x; af0[1]=(_Float16)xa.y;
        af0[2]=(_Float16)xa.z; af0[3]=(_Float16)xa.w;
        af0[4]=(_Float16)xb.x; af0[5]=(_Float16)xb.y;
        af0[6]=(_Float16)xb.z; af0[7]=(_Float16)xb.w;
        af1[0]=(_Float16)xc.x; af1[1]=(_Float16)xc.y;
        af1[2]=(_Float16)xc.z; af1[3]=(_Float16)xc.w;
        af1[4]=(_Float16)xd.x; af1[5]=(_Float16)xd.y;
        af1[6]=(_Float16)xd.z; af1[7]=(_Float16)xd.w;

        f32x4 a0 = {0.f,0.f,0.f,0.f}, a1 = {0.f,0.f,0.f,0.f};
        a0 = MFMA16(af0, bvt[0][0], a0);
        a0 = MFMA16(af1, bvt[0][1], a0);
        a1 = MFMA16(af0, bvt[1][0], a1);
        a1 = MFMA16(af1, bvt[1][1], a1);

        #pragma unroll
        for (int rr = 0; rr < 4; ++rr) {
            int v = mt*16 + kh*4 + rr;
            float w3r = w3v[mt][rr];
            s_fused[v*136 + (2*wv+0)*16 + r] =
                (_Float16)(fmaxf(a0[rr] + sbvt[0], 0.f) * w3r);
            s_fused[v*136 + (2*wv+1)*16 + r] =
                (_Float16)(fmaxf(a1[rr] + sbvt[1], 0.f) * w3r);
        }
    }

    // ---- gather combine: (1-w3d)*sum_c gw[c]*J_c -> s_j ----
    #pragma unroll
    for (int h = 0; h < 2; ++h) {
        half8 res;
        #pragma unroll
        for (int i = 0; i < 8; ++i) {
            float s = gw[0]*(float)jreg[0][h][i] + gw[1]*(float)jreg[1][h][i]
                    + gw[2]*(float)jreg[2][h][i] + gw[3]*(float)jreg[3][h][i];
            res[i] = (_Float16)(s * invw);
        }
        *(half8*)&s_j[vsv*72 + (h*4 + q_)*8] = res;
    }
    __syncthreads();                     // single barrier: s_fused + s_j ready

    // ---- phase 2: out = relu(fused @ w_f1_s^T + j + sb_f) ----
    #pragma unroll
    for (int mt = 0; mt < 4; ++mt) {
        f32x4 acc = {0.f,0.f,0.f,0.f};
        #pragma unroll
        for (int ks = 0; ks < 4; ++ks) {
            half8 af = *(const half8*)&s_fused[(mt*16 + r)*136 + ks*32 + kh*8];
            acc = MFMA16(af, bf1[ks], acc);
        }
        #pragma unroll
        for (int rr = 0; rr < 4; ++rr) {
            int v = mt*16 + kh*4 + rr;
            float jv = (float)s_j[v*72 + of];
            out[(size_t)(v0 + v)*OUTC + of] = fmaxf(acc[rr] + jv + sbf, 0.f);
        }
    }
}

// ---------------------------------------------------------------------------
extern "C" void kernel_launch(void* const* d_in, const int* in_sizes, int n_in,
                              void* d_out, int out_size, void* d_ws, size_t ws_size,
                              hipStream_t stream)
{
    const float* vf    = (const float*)d_in[0];
    const int*   vc    = (const int*)  d_in[1];
    const float* img   = (const float*)d_in[2];
    const float* gtb   = (const float*)d_in[3];
    const int*   gtc   = (const int*)  d_in[4];
    const float* w_vt  = (const float*)d_in[5];
    const float* b_vt  = (const float*)d_in[6];
    const float* g_vt  = (const float*)d_in[7];
    const float* be_vt = (const float*)d_in[8];
    const float* m_vt  = (const float*)d_in[9];
    const float* v_vt  = (const float*)d_in[10];
    const float* w_it  = (const float*)d_in[11];
    const float* b_it  = (const float*)d_in[12];
    const float* g_it  = (const float*)d_in[13];
    const float* be_it = (const float*)d_in[14];
    const float* m_it  = (const float*)d_in[15];
    const float* v_it  = (const float*)d_in[16];
    const float* w_f   = (const float*)d_in[17];
    const float* b_f   = (const float*)d_in[18];
    const float* g_f   = (const float*)d_in[19];
    const float* be_f  = (const float*)d_in[20];
    const float* m_f   = (const float*)d_in[21];
    const float* v_f   = (const float*)d_in[22];

    _Float16* ws_h   = (_Float16*)d_ws;
    _Float16* Jbuf   = ws_h;                              // B*IHW*64 halves
    _Float16* w_vt_s = ws_h + (size_t)BATCH*IHW*OUTC;     // 8192
    _Float16* w_it_s = w_vt_s + MIDC*C3D_;                // 32768
    _Float16* w_f1_s = w_it_s + MIDC*C2D_;                // 8192
    _Float16* w_f2_s = w_f1_s + OUTC*128;                 // 8192
    float*    fbase  = (float*)(w_f2_s + OUTC*128);
    float* sb_vt   = fbase;                               // 128
    float* sb_it   = sb_vt + MIDC;                        // 128
    float* sb_f    = sb_it + MIDC;                        // 64
    float* w3d_buf = sb_f + OUTC;                         // N_VOX
    float* outp = (float*)d_out;

    prep_all<<<N_VOX/256, 256, 0, stream>>>(
        vc, gtb, gtc,
        w_vt, g_vt, v_vt, b_vt, be_vt, m_vt,
        w_it, g_it, v_it, b_it, be_it, m_it,
        w_f,  g_f,  v_f,  b_f,  be_f,  m_f,
        w_vt_s, w_it_s, w_f1_s, w_f2_s,
        sb_vt, sb_it, sb_f, w3d_buf);

    img_transform<<<dim3(IHW/64, BATCH), 256, 0, stream>>>(
        img, w_it_s, w_f2_s, sb_it, Jbuf);

    voxel_fuse<<<N_VOX/64, 256, 0, stream>>>(
        vf, vc, w_vt_s, sb_vt, Jbuf, w_f1_s, sb_f, w3d_buf, outp);
}

// Round 17
// 86.878 us; speedup vs baseline: 1.4316x; 1.2391x over previous
//
#include <hip/hip_runtime.h>

typedef _Float16 half8  __attribute__((ext_vector_type(8)));
typedef _Float16 half4v __attribute__((ext_vector_type(4)));
typedef _Float16 half2v __attribute__((ext_vector_type(2)));
typedef float    f32x4  __attribute__((ext_vector_type(4)));

#define N_VOX  262144
#define BATCH  4
#define NBOX   32
#define C3D_   64
#define C2D_   256
#define MIDC   128
#define OUTC   64
#define IH     96
#define IW     312
#define IHW    (IH*IW)          // 29952
#define EPSF   1e-5f

#define MFMA16(a,b,c) __builtin_amdgcn_mfma_f32_16x16x32_f16(a,b,c,0,0,0)

// ---------------------------------------------------------------------------
// prep_all: (a) BN-folded fp16 weights + fp32 biases, (b) per-voxel w3d.
// ---------------------------------------------------------------------------
__global__ __launch_bounds__(256) void prep_all(
    const int*   __restrict__ coords,  // [N][4]
    const float* __restrict__ gtb,     // [B][32][7]
    const int*   __restrict__ gtc,     // [B][32]
    const float* __restrict__ w_vt, const float* __restrict__ g_vt,
    const float* __restrict__ v_vt, const float* __restrict__ b_vt,
    const float* __restrict__ be_vt, const float* __restrict__ m_vt,
    const float* __restrict__ w_it, const float* __restrict__ g_it,
    const float* __restrict__ v_it, const float* __restrict__ b_it,
    const float* __restrict__ be_it, const float* __restrict__ m_it,
    const float* __restrict__ w_f, const float* __restrict__ g_f,
    const float* __restrict__ v_f, const float* __restrict__ b_f,
    const float* __restrict__ be_f, const float* __restrict__ m_f,
    _Float16* __restrict__ w_vt_s, _Float16* __restrict__ w_it_s,
    _Float16* __restrict__ w_f1_s, _Float16* __restrict__ w_f2_s,
    float* __restrict__ sb_vt, float* __restrict__ sb_it,
    float* __restrict__ sb_f,  float* __restrict__ w3d_buf)
{
    __shared__ float s_box[BATCH*NBOX*7];
    __shared__ int   s_cls[BATCH*NBOX];
    const int tid = threadIdx.x;
    for (int i = tid; i < BATCH*NBOX*7; i += 256) s_box[i] = gtb[i];
    for (int i = tid; i < BATCH*NBOX;   i += 256) s_cls[i] = gtc[i];
    __syncthreads();

    const int v = blockIdx.x * 256 + tid;

    // ---- per-voxel class weight w3d ----
    {
        const int4 cc = ((const int4*)coords)[v];
        const int vb = cc.x;
        const float crx = cc.w * 0.05f;
        const float cry = cc.z * 0.05f - 40.0f;
        const float crz = cc.y * 0.1f  - 3.0f;
        const float* gb = s_box + vb*(NBOX*7);
        int lastm = -1;
        #pragma unroll 8
        for (int m = 0; m < NBOX; ++m) {
            float dx = gb[m*7+3];
            bool in = (fabsf(crx - gb[m*7+0]) < dx * 0.5f) &&
                      (fabsf(cry - gb[m*7+1]) < gb[m*7+4] * 0.5f) &&
                      (fabsf(crz - gb[m*7+2]) < gb[m*7+5] * 0.5f) &&
                      (dx > 0.f);
            if (in) lastm = m;
        }
        float w3 = 0.8f;
        if (lastm >= 0) {
            int cls = s_cls[vb*NBOX + lastm];
            w3 = (cls == 0) ? 0.85f : ((cls == 1) ? 0.95f : 0.6f);
        }
        w3d_buf[v] = w3;
    }

    // ---- BN-folded weights ----
    if (v < MIDC*C3D_) {
        int o = v >> 6;
        float sa = g_vt[o] * rsqrtf(v_vt[o] + EPSF);
        w_vt_s[v] = (_Float16)(w_vt[v] * sa);
    }
    if (v < MIDC*C2D_) {
        int o = v >> 8;
        float sa = g_it[o] * rsqrtf(v_it[o] + EPSF);
        w_it_s[v] = (_Float16)(w_it[v] * sa);
    }
    if (v < OUTC*C2D_) {
        int o = v >> 8, k = v & 255;
        float sa = g_f[o] * rsqrtf(v_f[o] + EPSF);
        float val = w_f[v] * sa;
        if (k < 128) w_f1_s[o*128 + k]       = (_Float16)val;
        else         w_f2_s[o*128 + (k-128)] = (_Float16)val;
    }
    if (v < MIDC) {
        float sa = g_vt[v] * rsqrtf(v_vt[v] + EPSF);
        sb_vt[v] = (b_vt[v] - m_vt[v]) * sa + be_vt[v];
        float si = g_it[v] * rsqrtf(v_it[v] + EPSF);
        sb_it[v] = (b_it[v] - m_it[v]) * si + be_it[v];
    }
    if (v < OUTC) {
        float sa = g_f[v] * rsqrtf(v_f[v] + EPSF);
        sb_f[v] = (b_f[v] - m_f[v]) * sa + be_f[v];
    }
}

// ---------------------------------------------------------------------------
// Kernel A: T = relu(img @ w_it_s^T + sb_it), J = T @ w_f2_s^T
// -> J[b][p][64] fp16.  (HBM-read-bound.)
// ---------------------------------------------------------------------------
__global__ __launch_bounds__(256, 4) void img_transform(
    const float* __restrict__ img,        // [B][256][H*W]
    const _Float16* __restrict__ w_it_s,  // [128][256] fp16, BN-folded
    const _Float16* __restrict__ w_f2_s,  // [64][128] fp16, BN-folded
    const float* __restrict__ sb_it,      // [128]
    _Float16* __restrict__ Jout)          // [B][H*W][64] fp16
{
    __shared__ __align__(16) _Float16 s_mem[64*136];

    const int p0   = blockIdx.x * 64;
    const int b    = blockIdx.y;
    const int tid  = threadIdx.x;
    const int lane = tid & 63;
    const int wv   = tid >> 6;
    const int r    = lane & 15;
    const int kh   = lane >> 4;

    f32x4 acc[4][2] = {};

    const int p  = tid & 63;
    const int cb = (tid >> 6) * 2;

    const float sbit0 = sb_it[wv*32 + r];
    const float sbit1 = sb_it[wv*32 + 16 + r];

    for (int kc = 0; kc < 4; ++kc) {
        #pragma unroll
        for (int i = 0; i < 8; ++i) {
            int c = cb + i*8;
            float x0 = img[(size_t)(b*C2D_ + kc*64 + c    )*IHW + p0 + p];
            float x1 = img[(size_t)(b*C2D_ + kc*64 + c + 1)*IHW + p0 + p];
            half2v h; h[0] = (_Float16)x0; h[1] = (_Float16)x1;
            *(half2v*)&s_mem[p*72 + c] = h;
        }
        half8 bw[2][2];
        #pragma unroll
        for (int nt = 0; nt < 2; ++nt)
            #pragma unroll
            for (int ks = 0; ks < 2; ++ks) {
                int o = wv*32 + nt*16 + r;
                bw[nt][ks] = *(const half8*)&w_it_s[o*C2D_ + kc*64 + ks*32 + kh*8];
            }
        __syncthreads();
        #pragma unroll
        for (int mt = 0; mt < 4; ++mt)
            #pragma unroll
            for (int ks = 0; ks < 2; ++ks) {
                half8 af = *(const half8*)&s_mem[(mt*16 + r)*72 + ks*32 + kh*8];
                acc[mt][0] = MFMA16(af, bw[0][ks], acc[mt][0]);
                acc[mt][1] = MFMA16(af, bw[1][ks], acc[mt][1]);
            }
        __syncthreads();
    }

    #pragma unroll
    for (int nt = 0; nt < 2; ++nt) {
        int o = wv*32 + nt*16 + r;
        float sb = nt ? sbit1 : sbit0;
        #pragma unroll
        for (int mt = 0; mt < 4; ++mt)
            #pragma unroll
            for (int rr = 0; rr < 4; ++rr) {
                int p2 = mt*16 + kh*4 + rr;
                s_mem[p2*136 + o] = (_Float16)fmaxf(acc[mt][nt][rr] + sb, 0.f);
            }
    }
    __syncthreads();

    {
        const int o2 = wv*16 + r;
        half8 bf2[4];
        #pragma unroll
        for (int ks = 0; ks < 4; ++ks)
            bf2[ks] = *(const half8*)&w_f2_s[o2*128 + ks*32 + kh*8];
        #pragma unroll
        for (int mt = 0; mt < 4; ++mt) {
            f32x4 a2 = {0.f,0.f,0.f,0.f};
            #pragma unroll
            for (int ks = 0; ks < 4; ++ks) {
                half8 af = *(const half8*)&s_mem[(mt*16 + r)*136 + ks*32 + kh*8];
                a2 = MFMA16(af, bf2[ks], a2);
            }
            #pragma unroll
            for (int rr = 0; rr < 4; ++rr) {
                int p2 = mt*16 + kh*4 + rr;
                Jout[(size_t)(b*IHW + p0 + p2)*OUTC + o2] = (_Float16)a2[rr];
            }
        }
    }
}

// ---------------------------------------------------------------------------
// Kernel B (round-8 structure, session best): 64 voxels/block, 4 blocks/CU.
// LDS-staged A, per-thread meta, J-gather issued AFTER bar1 so it hides
// under phase-1a MFMA; register-resident per-wave weights.
// ---------------------------------------------------------------------------
__global__ __launch_bounds__(256, 4) void voxel_fuse(
    const float* __restrict__ vf,         // [N][64]
    const int*   __restrict__ coords,     // [N][4]
    const _Float16* __restrict__ w_vt_s,  // [128][64] BN-folded
    const float* __restrict__ sb_vt,      // [128]
    const _Float16* __restrict__ Jimg,    // [B][H*W][64]
    const _Float16* __restrict__ w_f1_s,  // [64][128] BN-folded
    const float* __restrict__ sb_f,       // [64]
    const float* __restrict__ w3d_buf,    // [N]
    float* __restrict__ out)              // [N][64]
{
    __shared__ __align__(16) _Float16 s_vf[64*72];      // [v][k] pitch 72
    __shared__ __align__(16) _Float16 s_fused[64*136];  // [v][o] pitch 136
    __shared__ __align__(16) _Float16 s_j[64*72];       // [v][o] pitch 72
    __shared__ float s_w3d[64];

    const int tid  = threadIdx.x;
    const int lane = tid & 63;
    const int wv   = tid >> 6;
    const int v0   = blockIdx.x * 64;
    const int r    = lane & 15;
    const int kh   = lane >> 4;
    const int vsv  = tid >> 2;
    const int q_   = tid & 3;

    // ---- issue vf + w3d + coords loads ----
    float4 vfr[4];
    {
        const float4* src = (const float4*)(vf + (size_t)(v0 + vsv)*C3D_ + q_*16);
        #pragma unroll
        for (int i = 0; i < 4; ++i) vfr[i] = src[i];
    }
    const float w3 = w3d_buf[v0 + vsv];
    const int4 cc = ((const int4*)coords)[v0 + vsv];

    // ---- per-thread gather meta ----
    int ga[4]; float gw[4];
    {
        const int vb = cc.x;
        const float crx = cc.w * 0.05f;
        const float cry = cc.z * 0.05f - 40.0f;
        const float px = (crx + 0.025f) * 10.f + 156.f;
        const float py = (cry + 0.025f) * 10.f + 48.f;
        const float nx = fminf(fmaxf(px / 312.f * 2.f - 1.f, -1.f), 1.f);
        const float ny = fminf(fmaxf(py / 96.f  * 2.f - 1.f, -1.f), 1.f);
        const float fx = ((nx + 1.f) * 312.f - 1.f) * 0.5f;
        const float fy = ((ny + 1.f) * 96.f  - 1.f) * 0.5f;
        const float x0f = floorf(fx), y0f = floorf(fy);
        const float wx1 = fx - x0f, wy1 = fy - y0f;
        const int x0 = (int)x0f, y0 = (int)y0f;
        #pragma unroll
        for (int c = 0; c < 4; ++c) {
            int xi = x0 + (c & 1), yi = y0 + (c >> 1);
            bool valid = (xi >= 0) && (xi < IW) && (yi >= 0) && (yi < IH);
            int xc = min(max(xi, 0), IW - 1);
            int yc = min(max(yi, 0), IH - 1);
            ga[c] = ((vb*IH + yc)*IW + xc) * OUTC;
            float wx = (c & 1) ? wx1 : 1.f - wx1;
            float wy = (c >> 1) ? wy1 : 1.f - wy1;
            gw[c] = valid ? wx * wy : 0.f;
        }
    }

    // ---- weight fragments + biases (L2-hot) ----
    half8 bvt[2][2];
    float sbvt[2];
    #pragma unroll
    for (int nt = 0; nt < 2; ++nt) {
        int o = (2*wv + nt)*16 + r;
        #pragma unroll
        for (int ks = 0; ks < 2; ++ks)
            bvt[nt][ks] = *(const half8*)&w_vt_s[o*C3D_ + ks*32 + kh*8];
        sbvt[nt] = sb_vt[o];
    }
    const int of = wv*16 + r;
    half8 bf1[4];
    #pragma unroll
    for (int ks = 0; ks < 4; ++ks)
        bf1[ks] = *(const half8*)&w_f1_s[of*128 + ks*32 + kh*8];
    const float sbf = sb_f[of];

    // ---- stage vf -> fp16 LDS; publish w3d ----
    #pragma unroll
    for (int i = 0; i < 4; ++i) {
        float4 x = vfr[i];
        half4v h;
        h[0] = (_Float16)x.x; h[1] = (_Float16)x.y;
        h[2] = (_Float16)x.z; h[3] = (_Float16)x.w;
        *(half4v*)&s_vf[vsv*72 + q_*16 + i*4] = h;
    }
    if (q_ == 0) s_w3d[vsv] = w3;
    __syncthreads();

    // ---- issue J-gather AFTER bar1: hides under phase-1a MFMA ----
    half8 jreg[4][2];
    #pragma unroll
    for (int c = 0; c < 4; ++c)
        #pragma unroll
        for (int h = 0; h < 2; ++h)
            jreg[c][h] = *(const half8*)&Jimg[ga[c] + (h*4 + q_)*8];

    // ---- phase 1a: vt = relu(vf @ w_vt_s^T + sb) * w3d -> s_fused ----
    #pragma unroll
    for (int mt = 0; mt < 4; ++mt) {
        f32x4 a0 = {0.f,0.f,0.f,0.f}, a1 = {0.f,0.f,0.f,0.f};
        #pragma unroll
        for (int ks = 0; ks < 2; ++ks) {
            half8 af = *(const half8*)&s_vf[(mt*16 + r)*72 + ks*32 + kh*8];
            a0 = MFMA16(af, bvt[0][ks], a0);
            a1 = MFMA16(af, bvt[1][ks], a1);
        }
        #pragma unroll
        for (int rr = 0; rr < 4; ++rr) {
            int v = mt*16 + kh*4 + rr;
            float w3v = s_w3d[v];
            s_fused[v*136 + (2*wv+0)*16 + r] =
                (_Float16)(fmaxf(a0[rr] + sbvt[0], 0.f) * w3v);
            s_fused[v*136 + (2*wv+1)*16 + r] =
                (_Float16)(fmaxf(a1[rr] + sbvt[1], 0.f) * w3v);
        }
    }

    // ---- gather combine: (1-w3d)*sum_c gw[c]*J_c -> s_j ----
    {
        float invw = 1.f - w3;
        #pragma unroll
        for (int h = 0; h < 2; ++h) {
            half8 res;
            #pragma unroll
            for (int i = 0; i < 8; ++i) {
                float s = gw[0]*(float)jreg[0][h][i] + gw[1]*(float)jreg[1][h][i]
                        + gw[2]*(float)jreg[2][h][i] + gw[3]*(float)jreg[3][h][i];
                res[i] = (_Float16)(s * invw);
            }
            *(half8*)&s_j[vsv*72 + (h*4 + q_)*8] = res;
        }
    }
    __syncthreads();

    // ---- phase 2: out = relu(fused @ w_f1_s^T + j + sb_f) ----
    #pragma unroll
    for (int mt = 0; mt < 4; ++mt) {
        f32x4 acc = {0.f,0.f,0.f,0.f};
        #pragma unroll
        for (int ks = 0; ks < 4; ++ks) {
            half8 af = *(const half8*)&s_fused[(mt*16 + r)*136 + ks*32 + kh*8];
            acc = MFMA16(af, bf1[ks], acc);
        }
        #pragma unroll
        for (int rr = 0; rr < 4; ++rr) {
            int v = mt*16 + kh*4 + rr;
            float jv = (float)s_j[v*72 + of];
            out[(size_t)(v0 + v)*OUTC + of] = fmaxf(acc[rr] + jv + sbf, 0.f);
        }
    }
}

// ---------------------------------------------------------------------------
extern "C" void kernel_launch(void* const* d_in, const int* in_sizes, int n_in,
                              void* d_out, int out_size, void* d_ws, size_t ws_size,
                              hipStream_t stream)
{
    const float* vf    = (const float*)d_in[0];
    const int*   vc    = (const int*)  d_in[1];
    const float* img   = (const float*)d_in[2];
    const float* gtb   = (const float*)d_in[3];
    const int*   gtc   = (const int*)  d_in[4];
    const float* w_vt  = (const float*)d_in[5];
    const float* b_vt  = (const float*)d_in[6];
    const float* g_vt  = (const float*)d_in[7];
    const float* be_vt = (const float*)d_in[8];
    const float* m_vt  = (const float*)d_in[9];
    const float* v_vt  = (const float*)d_in[10];
    const float* w_it  = (const float*)d_in[11];
    const float* b_it  = (const float*)d_in[12];
    const float* g_it  = (const float*)d_in[13];
    const float* be_it = (const float*)d_in[14];
    const float* m_it  = (const float*)d_in[15];
    const float* v_it  = (const float*)d_in[16];
    const float* w_f   = (const float*)d_in[17];
    const float* b_f   = (const float*)d_in[18];
    const float* g_f   = (const float*)d_in[19];
    const float* be_f  = (const float*)d_in[20];
    const float* m_f   = (const float*)d_in[21];
    const float* v_f   = (const float*)d_in[22];

    _Float16* ws_h   = (_Float16*)d_ws;
    _Float16* Jbuf   = ws_h;                              // B*IHW*64 halves
    _Float16* w_vt_s = ws_h + (size_t)BATCH*IHW*OUTC;     // 8192
    _Float16* w_it_s = w_vt_s + MIDC*C3D_;                // 32768
    _Float16* w_f1_s = w_it_s + MIDC*C2D_;                // 8192
    _Float16* w_f2_s = w_f1_s + OUTC*128;                 // 8192
    float*    fbase  = (float*)(w_f2_s + OUTC*128);
    float* sb_vt   = fbase;                               // 128
    float* sb_it   = sb_vt + MIDC;                        // 128
    float* sb_f    = sb_it + MIDC;                        // 64
    float* w3d_buf = sb_f + OUTC;                         // N_VOX
    float* outp = (float*)d_out;

    prep_all<<<N_VOX/256, 256, 0, stream>>>(
        vc, gtb, gtc,
        w_vt, g_vt, v_vt, b_vt, be_vt, m_vt,
        w_it, g_it, v_it, b_it, be_it, m_it,
        w_f,  g_f,  v_f,  b_f,  be_f,  m_f,
        w_vt_s, w_it_s, w_f1_s, w_f2_s,
        sb_vt, sb_it, sb_f, w3d_buf);

    img_transform<<<dim3(IHW/64, BATCH), 256, 0, stream>>>(
        img, w_it_s, w_f2_s, sb_it, Jbuf);

    voxel_fuse<<<N_VOX/64, 256, 0, stream>>>(
        vf, vc, w_vt_s, sb_vt, Jbuf, w_f1_s, sb_f, w3d_buf, outp);
}

// Round 18
// 85.830 us; speedup vs baseline: 1.4490x; 1.0122x over previous
//
#include <hip/hip_runtime.h>

typedef _Float16 half8  __attribute__((ext_vector_type(8)));
typedef _Float16 half4v __attribute__((ext_vector_type(4)));
typedef _Float16 half2v __attribute__((ext_vector_type(2)));
typedef float    f32x4  __attribute__((ext_vector_type(4)));

#define N_VOX  262144
#define BATCH  4
#define NBOX   32
#define C3D_   64
#define C2D_   256
#define MIDC   128
#define OUTC   64
#define IH     96
#define IW     312
#define IHW    (IH*IW)          // 29952
#define EPSF   1e-5f

#define MFMA16(a,b,c) __builtin_amdgcn_mfma_f32_16x16x32_f16(a,b,c,0,0,0)

// ---------------------------------------------------------------------------
// prep_all: (a) BN-folded fp16 weights + fp32 biases, (b) per-voxel w3d.
// ---------------------------------------------------------------------------
__global__ __launch_bounds__(256) void prep_all(
    const int*   __restrict__ coords,  // [N][4]
    const float* __restrict__ gtb,     // [B][32][7]
    const int*   __restrict__ gtc,     // [B][32]
    const float* __restrict__ w_vt, const float* __restrict__ g_vt,
    const float* __restrict__ v_vt, const float* __restrict__ b_vt,
    const float* __restrict__ be_vt, const float* __restrict__ m_vt,
    const float* __restrict__ w_it, const float* __restrict__ g_it,
    const float* __restrict__ v_it, const float* __restrict__ b_it,
    const float* __restrict__ be_it, const float* __restrict__ m_it,
    const float* __restrict__ w_f, const float* __restrict__ g_f,
    const float* __restrict__ v_f, const float* __restrict__ b_f,
    const float* __restrict__ be_f, const float* __restrict__ m_f,
    _Float16* __restrict__ w_vt_s, _Float16* __restrict__ w_it_s,
    _Float16* __restrict__ w_f1_s, _Float16* __restrict__ w_f2_s,
    float* __restrict__ sb_vt, float* __restrict__ sb_it,
    float* __restrict__ sb_f,  float* __restrict__ w3d_buf)
{
    __shared__ float s_box[BATCH*NBOX*7];
    __shared__ int   s_cls[BATCH*NBOX];
    const int tid = threadIdx.x;
    for (int i = tid; i < BATCH*NBOX*7; i += 256) s_box[i] = gtb[i];
    for (int i = tid; i < BATCH*NBOX;   i += 256) s_cls[i] = gtc[i];
    __syncthreads();

    const int v = blockIdx.x * 256 + tid;

    // ---- per-voxel class weight w3d ----
    {
        const int4 cc = ((const int4*)coords)[v];
        const int vb = cc.x;
        const float crx = cc.w * 0.05f;
        const float cry = cc.z * 0.05f - 40.0f;
        const float crz = cc.y * 0.1f  - 3.0f;
        const float* gb = s_box + vb*(NBOX*7);
        int lastm = -1;
        #pragma unroll 8
        for (int m = 0; m < NBOX; ++m) {
            float dx = gb[m*7+3];
            bool in = (fabsf(crx - gb[m*7+0]) < dx * 0.5f) &&
                      (fabsf(cry - gb[m*7+1]) < gb[m*7+4] * 0.5f) &&
                      (fabsf(crz - gb[m*7+2]) < gb[m*7+5] * 0.5f) &&
                      (dx > 0.f);
            if (in) lastm = m;
        }
        float w3 = 0.8f;
        if (lastm >= 0) {
            int cls = s_cls[vb*NBOX + lastm];
            w3 = (cls == 0) ? 0.85f : ((cls == 1) ? 0.95f : 0.6f);
        }
        w3d_buf[v] = w3;
    }

    // ---- BN-folded weights ----
    if (v < MIDC*C3D_) {
        int o = v >> 6;
        float sa = g_vt[o] * rsqrtf(v_vt[o] + EPSF);
        w_vt_s[v] = (_Float16)(w_vt[v] * sa);
    }
    if (v < MIDC*C2D_) {
        int o = v >> 8;
        float sa = g_it[o] * rsqrtf(v_it[o] + EPSF);
        w_it_s[v] = (_Float16)(w_it[v] * sa);
    }
    if (v < OUTC*C2D_) {
        int o = v >> 8, k = v & 255;
        float sa = g_f[o] * rsqrtf(v_f[o] + EPSF);
        float val = w_f[v] * sa;
        if (k < 128) w_f1_s[o*128 + k]       = (_Float16)val;
        else         w_f2_s[o*128 + (k-128)] = (_Float16)val;
    }
    if (v < MIDC) {
        float sa = g_vt[v] * rsqrtf(v_vt[v] + EPSF);
        sb_vt[v] = (b_vt[v] - m_vt[v]) * sa + be_vt[v];
        float si = g_it[v] * rsqrtf(v_it[v] + EPSF);
        sb_it[v] = (b_it[v] - m_it[v]) * si + be_it[v];
    }
    if (v < OUTC) {
        float sa = g_f[v] * rsqrtf(v_f[v] + EPSF);
        sb_f[v] = (b_f[v] - m_f[v]) * sa + be_f[v];
    }
}

// ---------------------------------------------------------------------------
// Kernel A: T = relu(img @ w_it_s^T + sb_it), J = T @ w_f2_s^T
// -> J[b][p][64] fp16.  (HBM-read-bound.)
// ---------------------------------------------------------------------------
__global__ __launch_bounds__(256, 4) void img_transform(
    const float* __restrict__ img,        // [B][256][H*W]
    const _Float16* __restrict__ w_it_s,  // [128][256] fp16, BN-folded
    const _Float16* __restrict__ w_f2_s,  // [64][128] fp16, BN-folded
    const float* __restrict__ sb_it,      // [128]
    _Float16* __restrict__ Jout)          // [B][H*W][64] fp16
{
    __shared__ __align__(16) _Float16 s_mem[64*136];

    const int p0   = blockIdx.x * 64;
    const int b    = blockIdx.y;
    const int tid  = threadIdx.x;
    const int lane = tid & 63;
    const int wv   = tid >> 6;
    const int r    = lane & 15;
    const int kh   = lane >> 4;

    f32x4 acc[4][2] = {};

    const int p  = tid & 63;
    const int cb = (tid >> 6) * 2;

    const float sbit0 = sb_it[wv*32 + r];
    const float sbit1 = sb_it[wv*32 + 16 + r];

    for (int kc = 0; kc < 4; ++kc) {
        #pragma unroll
        for (int i = 0; i < 8; ++i) {
            int c = cb + i*8;
            float x0 = img[(size_t)(b*C2D_ + kc*64 + c    )*IHW + p0 + p];
            float x1 = img[(size_t)(b*C2D_ + kc*64 + c + 1)*IHW + p0 + p];
            half2v h; h[0] = (_Float16)x0; h[1] = (_Float16)x1;
            *(half2v*)&s_mem[p*72 + c] = h;
        }
        half8 bw[2][2];
        #pragma unroll
        for (int nt = 0; nt < 2; ++nt)
            #pragma unroll
            for (int ks = 0; ks < 2; ++ks) {
                int o = wv*32 + nt*16 + r;
                bw[nt][ks] = *(const half8*)&w_it_s[o*C2D_ + kc*64 + ks*32 + kh*8];
            }
        __syncthreads();
        #pragma unroll
        for (int mt = 0; mt < 4; ++mt)
            #pragma unroll
            for (int ks = 0; ks < 2; ++ks) {
                half8 af = *(const half8*)&s_mem[(mt*16 + r)*72 + ks*32 + kh*8];
                acc[mt][0] = MFMA16(af, bw[0][ks], acc[mt][0]);
                acc[mt][1] = MFMA16(af, bw[1][ks], acc[mt][1]);
            }
        __syncthreads();
    }

    #pragma unroll
    for (int nt = 0; nt < 2; ++nt) {
        int o = wv*32 + nt*16 + r;
        float sb = nt ? sbit1 : sbit0;
        #pragma unroll
        for (int mt = 0; mt < 4; ++mt)
            #pragma unroll
            for (int rr = 0; rr < 4; ++rr) {
                int p2 = mt*16 + kh*4 + rr;
                s_mem[p2*136 + o] = (_Float16)fmaxf(acc[mt][nt][rr] + sb, 0.f);
            }
    }
    __syncthreads();

    {
        const int o2 = wv*16 + r;
        half8 bf2[4];
        #pragma unroll
        for (int ks = 0; ks < 4; ++ks)
            bf2[ks] = *(const half8*)&w_f2_s[o2*128 + ks*32 + kh*8];
        #pragma unroll
        for (int mt = 0; mt < 4; ++mt) {
            f32x4 a2 = {0.f,0.f,0.f,0.f};
            #pragma unroll
            for (int ks = 0; ks < 4; ++ks) {
                half8 af = *(const half8*)&s_mem[(mt*16 + r)*136 + ks*32 + kh*8];
                a2 = MFMA16(af, bf2[ks], a2);
            }
            #pragma unroll
            for (int rr = 0; rr < 4; ++rr) {
                int p2 = mt*16 + kh*4 + rr;
                Jout[(size_t)(b*IHW + p0 + p2)*OUTC + o2] = (_Float16)a2[rr];
            }
        }
    }
}

// ---------------------------------------------------------------------------
// Kernel B (round-8 structure; ONE delta: J-gather issued BEFORE the vf
// stage so its L2/L3 latency drains concurrently with vfr at bar1, instead
// of being exposed after phase 1a).
// ---------------------------------------------------------------------------
__global__ __launch_bounds__(256, 4) void voxel_fuse(
    const float* __restrict__ vf,         // [N][64]
    const int*   __restrict__ coords,     // [N][4]
    const _Float16* __restrict__ w_vt_s,  // [128][64] BN-folded
    const float* __restrict__ sb_vt,      // [128]
    const _Float16* __restrict__ Jimg,    // [B][H*W][64]
    const _Float16* __restrict__ w_f1_s,  // [64][128] BN-folded
    const float* __restrict__ sb_f,       // [64]
    const float* __restrict__ w3d_buf,    // [N]
    float* __restrict__ out)              // [N][64]
{
    __shared__ __align__(16) _Float16 s_vf[64*72];      // [v][k] pitch 72
    __shared__ __align__(16) _Float16 s_fused[64*136];  // [v][o] pitch 136
    __shared__ __align__(16) _Float16 s_j[64*72];       // [v][o] pitch 72
    __shared__ float s_w3d[64];

    const int tid  = threadIdx.x;
    const int lane = tid & 63;
    const int wv   = tid >> 6;
    const int v0   = blockIdx.x * 64;
    const int r    = lane & 15;
    const int kh   = lane >> 4;
    const int vsv  = tid >> 2;
    const int q_   = tid & 3;

    // ---- issue vf + w3d + coords loads ----
    float4 vfr[4];
    {
        const float4* src = (const float4*)(vf + (size_t)(v0 + vsv)*C3D_ + q_*16);
        #pragma unroll
        for (int i = 0; i < 4; ++i) vfr[i] = src[i];
    }
    const float w3 = w3d_buf[v0 + vsv];
    const int4 cc = ((const int4*)coords)[v0 + vsv];

    // ---- per-thread gather meta ----
    int ga[4]; float gw[4];
    {
        const int vb = cc.x;
        const float crx = cc.w * 0.05f;
        const float cry = cc.z * 0.05f - 40.0f;
        const float px = (crx + 0.025f) * 10.f + 156.f;
        const float py = (cry + 0.025f) * 10.f + 48.f;
        const float nx = fminf(fmaxf(px / 312.f * 2.f - 1.f, -1.f), 1.f);
        const float ny = fminf(fmaxf(py / 96.f  * 2.f - 1.f, -1.f), 1.f);
        const float fx = ((nx + 1.f) * 312.f - 1.f) * 0.5f;
        const float fy = ((ny + 1.f) * 96.f  - 1.f) * 0.5f;
        const float x0f = floorf(fx), y0f = floorf(fy);
        const float wx1 = fx - x0f, wy1 = fy - y0f;
        const int x0 = (int)x0f, y0 = (int)y0f;
        #pragma unroll
        for (int c = 0; c < 4; ++c) {
            int xi = x0 + (c & 1), yi = y0 + (c >> 1);
            bool valid = (xi >= 0) && (xi < IW) && (yi >= 0) && (yi < IH);
            int xc = min(max(xi, 0), IW - 1);
            int yc = min(max(yi, 0), IH - 1);
            ga[c] = ((vb*IH + yc)*IW + xc) * OUTC;
            float wx = (c & 1) ? wx1 : 1.f - wx1;
            float wy = (c >> 1) ? wy1 : 1.f - wy1;
            gw[c] = valid ? wx * wy : 0.f;
        }
    }

    // ---- issue J-gather NOW (drains at bar1 concurrently with vfr) ----
    half8 jreg[4][2];
    #pragma unroll
    for (int c = 0; c < 4; ++c)
        #pragma unroll
        for (int h = 0; h < 2; ++h)
            jreg[c][h] = *(const half8*)&Jimg[ga[c] + (h*4 + q_)*8];

    // ---- weight fragments + biases (L2-hot) ----
    half8 bvt[2][2];
    float sbvt[2];
    #pragma unroll
    for (int nt = 0; nt < 2; ++nt) {
        int o = (2*wv + nt)*16 + r;
        #pragma unroll
        for (int ks = 0; ks < 2; ++ks)
            bvt[nt][ks] = *(const half8*)&w_vt_s[o*C3D_ + ks*32 + kh*8];
        sbvt[nt] = sb_vt[o];
    }
    const int of = wv*16 + r;
    half8 bf1[4];
    #pragma unroll
    for (int ks = 0; ks < 4; ++ks)
        bf1[ks] = *(const half8*)&w_f1_s[of*128 + ks*32 + kh*8];
    const float sbf = sb_f[of];

    // ---- stage vf -> fp16 LDS; publish w3d ----
    #pragma unroll
    for (int i = 0; i < 4; ++i) {
        float4 x = vfr[i];
        half4v h;
        h[0] = (_Float16)x.x; h[1] = (_Float16)x.y;
        h[2] = (_Float16)x.z; h[3] = (_Float16)x.w;
        *(half4v*)&s_vf[vsv*72 + q_*16 + i*4] = h;
    }
    if (q_ == 0) s_w3d[vsv] = w3;
    __syncthreads();

    // ---- phase 1a: vt = relu(vf @ w_vt_s^T + sb) * w3d -> s_fused ----
    #pragma unroll
    for (int mt = 0; mt < 4; ++mt) {
        f32x4 a0 = {0.f,0.f,0.f,0.f}, a1 = {0.f,0.f,0.f,0.f};
        #pragma unroll
        for (int ks = 0; ks < 2; ++ks) {
            half8 af = *(const half8*)&s_vf[(mt*16 + r)*72 + ks*32 + kh*8];
            a0 = MFMA16(af, bvt[0][ks], a0);
            a1 = MFMA16(af, bvt[1][ks], a1);
        }
        #pragma unroll
        for (int rr = 0; rr < 4; ++rr) {
            int v = mt*16 + kh*4 + rr;
            float w3v = s_w3d[v];
            s_fused[v*136 + (2*wv+0)*16 + r] =
                (_Float16)(fmaxf(a0[rr] + sbvt[0], 0.f) * w3v);
            s_fused[v*136 + (2*wv+1)*16 + r] =
                (_Float16)(fmaxf(a1[rr] + sbvt[1], 0.f) * w3v);
        }
    }

    // ---- gather combine: (1-w3d)*sum_c gw[c]*J_c -> s_j ----
    {
        float invw = 1.f - w3;
        #pragma unroll
        for (int h = 0; h < 2; ++h) {
            half8 res;
            #pragma unroll
            for (int i = 0; i < 8; ++i) {
                float s = gw[0]*(float)jreg[0][h][i] + gw[1]*(float)jreg[1][h][i]
                        + gw[2]*(float)jreg[2][h][i] + gw[3]*(float)jreg[3][h][i];
                res[i] = (_Float16)(s * invw);
            }
            *(half8*)&s_j[vsv*72 + (h*4 + q_)*8] = res;
        }
    }
    __syncthreads();

    // ---- phase 2: out = relu(fused @ w_f1_s^T + j + sb_f) ----
    #pragma unroll
    for (int mt = 0; mt < 4; ++mt) {
        f32x4 acc = {0.f,0.f,0.f,0.f};
        #pragma unroll
        for (int ks = 0; ks < 4; ++ks) {
            half8 af = *(const half8*)&s_fused[(mt*16 + r)*136 + ks*32 + kh*8];
            acc = MFMA16(af, bf1[ks], acc);
        }
        #pragma unroll
        for (int rr = 0; rr < 4; ++rr) {
            int v = mt*16 + kh*4 + rr;
            float jv = (float)s_j[v*72 + of];
            out[(size_t)(v0 + v)*OUTC + of] = fmaxf(acc[rr] + jv + sbf, 0.f);
        }
    }
}

// ---------------------------------------------------------------------------
extern "C" void kernel_launch(void* const* d_in, const int* in_sizes, int n_in,
                              void* d_out, int out_size, void* d_ws, size_t ws_size,
                              hipStream_t stream)
{
    const float* vf    = (const float*)d_in[0];
    const int*   vc    = (const int*)  d_in[1];
    const float* img   = (const float*)d_in[2];
    const float* gtb   = (const float*)d_in[3];
    const int*   gtc   = (const int*)  d_in[4];
    const float* w_vt  = (const float*)d_in[5];
    const float* b_vt  = (const float*)d_in[6];
    const float* g_vt  = (const float*)d_in[7];
    const float* be_vt = (const float*)d_in[8];
    const float* m_vt  = (const float*)d_in[9];
    const float* v_vt  = (const float*)d_in[10];
    const float* w_it  = (const float*)d_in[11];
    const float* b_it  = (const float*)d_in[12];
    const float* g_it  = (const float*)d_in[13];
    const float* be_it = (const float*)d_in[14];
    const float* m_it  = (const float*)d_in[15];
    const float* v_it  = (const float*)d_in[16];
    const float* w_f   = (const float*)d_in[17];
    const float* b_f   = (const float*)d_in[18];
    const float* g_f   = (const float*)d_in[19];
    const float* be_f  = (const float*)d_in[20];
    const float* m_f   = (const float*)d_in[21];
    const float* v_f   = (const float*)d_in[22];

    _Float16* ws_h   = (_Float16*)d_ws;
    _Float16* Jbuf   = ws_h;                              // B*IHW*64 halves
    _Float16* w_vt_s = ws_h + (size_t)BATCH*IHW*OUTC;     // 8192
    _Float16* w_it_s = w_vt_s + MIDC*C3D_;                // 32768
    _Float16* w_f1_s = w_it_s + MIDC*C2D_;                // 8192
    _Float16* w_f2_s = w_f1_s + OUTC*128;                 // 8192
    float*    fbase  = (float*)(w_f2_s + OUTC*128);
    float* sb_vt   = fbase;                               // 128
    float* sb_it   = sb_vt + MIDC;                        // 128
    float* sb_f    = sb_it + MIDC;                        // 64
    float* w3d_buf = sb_f + OUTC;                         // N_VOX
    float* outp = (float*)d_out;

    prep_all<<<N_VOX/256, 256, 0, stream>>>(
        vc, gtb, gtc,
        w_vt, g_vt, v_vt, b_vt, be_vt, m_vt,
        w_it, g_it, v_it, b_it, be_it, m_it,
        w_f,  g_f,  v_f,  b_f,  be_f,  m_f,
        w_vt_s, w_it_s, w_f1_s, w_f2_s,
        sb_vt, sb_it, sb_f, w3d_buf);

    img_transform<<<dim3(IHW/64, BATCH), 256, 0, stream>>>(
        img, w_it_s, w_f2_s, sb_it, Jbuf);

    voxel_fuse<<<N_VOX/64, 256, 0, stream>>>(
        vf, vc, w_vt_s, sb_vt, Jbuf, w_f1_s, sb_f, w3d_buf, outp);
}

// Round 20
// 84.695 us; speedup vs baseline: 1.4685x; 1.0134x over previous
//
#include <hip/hip_runtime.h>

typedef _Float16 half8  __attribute__((ext_vector_type(8)));
typedef _Float16 half4v __attribute__((ext_vector_type(4)));
typedef _Float16 half2v __attribute__((ext_vector_type(2)));
typedef float    f32x4  __attribute__((ext_vector_type(4)));

#define N_VOX  262144
#define BATCH  4
#define NBOX   32
#define C3D_   64
#define C2D_   256
#define MIDC   128
#define OUTC   64
#define IH     96
#define IW     312
#define IHW    (IH*IW)          // 29952
#define EPSF   1e-5f

#define MFMA16(a,b,c) __builtin_amdgcn_mfma_f32_16x16x32_f16(a,b,c,0,0,0)

// ---------------------------------------------------------------------------
// prep_all: (a) BN-folded fp16 weights + fp32 biases, (b) per-voxel w3d.
// ---------------------------------------------------------------------------
__global__ __launch_bounds__(256) void prep_all(
    const int*   __restrict__ coords,  // [N][4]
    const float* __restrict__ gtb,     // [B][32][7]
    const int*   __restrict__ gtc,     // [B][32]
    const float* __restrict__ w_vt, const float* __restrict__ g_vt,
    const float* __restrict__ v_vt, const float* __restrict__ b_vt,
    const float* __restrict__ be_vt, const float* __restrict__ m_vt,
    const float* __restrict__ w_it, const float* __restrict__ g_it,
    const float* __restrict__ v_it, const float* __restrict__ b_it,
    const float* __restrict__ be_it, const float* __restrict__ m_it,
    const float* __restrict__ w_f, const float* __restrict__ g_f,
    const float* __restrict__ v_f, const float* __restrict__ b_f,
    const float* __restrict__ be_f, const float* __restrict__ m_f,
    _Float16* __restrict__ w_vt_s, _Float16* __restrict__ w_it_s,
    _Float16* __restrict__ w_f1_s, _Float16* __restrict__ w_f2_s,
    float* __restrict__ sb_vt, float* __restrict__ sb_it,
    float* __restrict__ sb_f,  float* __restrict__ w3d_buf)
{
    __shared__ float s_box[BATCH*NBOX*7];
    __shared__ int   s_cls[BATCH*NBOX];
    const int tid = threadIdx.x;
    for (int i = tid; i < BATCH*NBOX*7; i += 256) s_box[i] = gtb[i];
    for (int i = tid; i < BATCH*NBOX;   i += 256) s_cls[i] = gtc[i];
    __syncthreads();

    const int v = blockIdx.x * 256 + tid;

    // ---- per-voxel class weight w3d ----
    {
        const int4 cc = ((const int4*)coords)[v];
        const int vb = cc.x;
        const float crx = cc.w * 0.05f;
        const float cry = cc.z * 0.05f - 40.0f;
        const float crz = cc.y * 0.1f  - 3.0f;
        const float* gb = s_box + vb*(NBOX*7);
        int lastm = -1;
        #pragma unroll 8
        for (int m = 0; m < NBOX; ++m) {
            float dx = gb[m*7+3];
            bool in = (fabsf(crx - gb[m*7+0]) < dx * 0.5f) &&
                      (fabsf(cry - gb[m*7+1]) < gb[m*7+4] * 0.5f) &&
                      (fabsf(crz - gb[m*7+2]) < gb[m*7+5] * 0.5f) &&
                      (dx > 0.f);
            if (in) lastm = m;
        }
        float w3 = 0.8f;
        if (lastm >= 0) {
            int cls = s_cls[vb*NBOX + lastm];
            w3 = (cls == 0) ? 0.85f : ((cls == 1) ? 0.95f : 0.6f);
        }
        w3d_buf[v] = w3;
    }

    // ---- BN-folded weights ----
    if (v < MIDC*C3D_) {
        int o = v >> 6;
        float sa = g_vt[o] * rsqrtf(v_vt[o] + EPSF);
        w_vt_s[v] = (_Float16)(w_vt[v] * sa);
    }
    if (v < MIDC*C2D_) {
        int o = v >> 8;
        float sa = g_it[o] * rsqrtf(v_it[o] + EPSF);
        w_it_s[v] = (_Float16)(w_it[v] * sa);
    }
    if (v < OUTC*C2D_) {
        int o = v >> 8, k = v & 255;
        float sa = g_f[o] * rsqrtf(v_f[o] + EPSF);
        float val = w_f[v] * sa;
        if (k < 128) w_f1_s[o*128 + k]       = (_Float16)val;
        else         w_f2_s[o*128 + (k-128)] = (_Float16)val;
    }
    if (v < MIDC) {
        float sa = g_vt[v] * rsqrtf(v_vt[v] + EPSF);
        sb_vt[v] = (b_vt[v] - m_vt[v]) * sa + be_vt[v];
        float si = g_it[v] * rsqrtf(v_it[v] + EPSF);
        sb_it[v] = (b_it[v] - m_it[v]) * si + be_it[v];
    }
    if (v < OUTC) {
        float sa = g_f[v] * rsqrtf(v_f[v] + EPSF);
        sb_f[v] = (b_f[v] - m_f[v]) * sa + be_f[v];
    }
}

// ---------------------------------------------------------------------------
// Kernel A: T = relu(img @ w_it_s^T + sb_it), J = T @ w_f2_s^T
// -> J[b][p][64] fp16.  (HBM-read-bound.)
// ---------------------------------------------------------------------------
__global__ __launch_bounds__(256, 4) void img_transform(
    const float* __restrict__ img,        // [B][256][H*W]
    const _Float16* __restrict__ w_it_s,  // [128][256] fp16, BN-folded
    const _Float16* __restrict__ w_f2_s,  // [64][128] fp16, BN-folded
    const float* __restrict__ sb_it,      // [128]
    _Float16* __restrict__ Jout)          // [B][H*W][64] fp16
{
    __shared__ __align__(16) _Float16 s_mem[64*136];

    const int p0   = blockIdx.x * 64;
    const int b    = blockIdx.y;
    const int tid  = threadIdx.x;
    const int lane = tid & 63;
    const int wv   = tid >> 6;
    const int r    = lane & 15;
    const int kh   = lane >> 4;

    f32x4 acc[4][2] = {};

    const int p  = tid & 63;
    const int cb = (tid >> 6) * 2;

    const float sbit0 = sb_it[wv*32 + r];
    const float sbit1 = sb_it[wv*32 + 16 + r];

    for (int kc = 0; kc < 4; ++kc) {
        #pragma unroll
        for (int i = 0; i < 8; ++i) {
            int c = cb + i*8;
            float x0 = img[(size_t)(b*C2D_ + kc*64 + c    )*IHW + p0 + p];
            float x1 = img[(size_t)(b*C2D_ + kc*64 + c + 1)*IHW + p0 + p];
            half2v h; h[0] = (_Float16)x0; h[1] = (_Float16)x1;
            *(half2v*)&s_mem[p*72 + c] = h;
        }
        half8 bw[2][2];
        #pragma unroll
        for (int nt = 0; nt < 2; ++nt)
            #pragma unroll
            for (int ks = 0; ks < 2; ++ks) {
                int o = wv*32 + nt*16 + r;
                bw[nt][ks] = *(const half8*)&w_it_s[o*C2D_ + kc*64 + ks*32 + kh*8];
            }
        __syncthreads();
        #pragma unroll
        for (int mt = 0; mt < 4; ++mt)
            #pragma unroll
            for (int ks = 0; ks < 2; ++ks) {
                half8 af = *(const half8*)&s_mem[(mt*16 + r)*72 + ks*32 + kh*8];
                acc[mt][0] = MFMA16(af, bw[0][ks], acc[mt][0]);
                acc[mt][1] = MFMA16(af, bw[1][ks], acc[mt][1]);
            }
        __syncthreads();
    }

    #pragma unroll
    for (int nt = 0; nt < 2; ++nt) {
        int o = wv*32 + nt*16 + r;
        float sb = nt ? sbit1 : sbit0;
        #pragma unroll
        for (int mt = 0; mt < 4; ++mt)
            #pragma unroll
            for (int rr = 0; rr < 4; ++rr) {
                int p2 = mt*16 + kh*4 + rr;
                s_mem[p2*136 + o] = (_Float16)fmaxf(acc[mt][nt][rr] + sb, 0.f);
            }
    }
    __syncthreads();

    {
        const int o2 = wv*16 + r;
        half8 bf2[4];
        #pragma unroll
        for (int ks = 0; ks < 4; ++ks)
            bf2[ks] = *(const half8*)&w_f2_s[o2*128 + ks*32 + kh*8];
        #pragma unroll
        for (int mt = 0; mt < 4; ++mt) {
            f32x4 a2 = {0.f,0.f,0.f,0.f};
            #pragma unroll
            for (int ks = 0; ks < 4; ++ks) {
                half8 af = *(const half8*)&s_mem[(mt*16 + r)*136 + ks*32 + kh*8];
                a2 = MFMA16(af, bf2[ks], a2);
            }
            #pragma unroll
            for (int rr = 0; rr < 4; ++rr) {
                int p2 = mt*16 + kh*4 + rr;
                Jout[(size_t)(b*IHW + p0 + p2)*OUTC + o2] = (_Float16)a2[rr];
            }
        }
    }
}

// ---------------------------------------------------------------------------
// Kernel B (R18 structure; ONE delta: __launch_bounds__(256,3) lifts the
// 64-VGPR cap so {vfr, jreg, weights} can stay in flight concurrently).
// ---------------------------------------------------------------------------
__global__ __launch_bounds__(256, 3) void voxel_fuse(
    const float* __restrict__ vf,         // [N][64]
    const int*   __restrict__ coords,     // [N][4]
    const _Float16* __restrict__ w_vt_s,  // [128][64] BN-folded
    const float* __restrict__ sb_vt,      // [128]
    const _Float16* __restrict__ Jimg,    // [B][H*W][64]
    const _Float16* __restrict__ w_f1_s,  // [64][128] BN-folded
    const float* __restrict__ sb_f,       // [64]
    const float* __restrict__ w3d_buf,    // [N]
    float* __restrict__ out)              // [N][64]
{
    __shared__ __align__(16) _Float16 s_vf[64*72];      // [v][k] pitch 72
    __shared__ __align__(16) _Float16 s_fused[64*136];  // [v][o] pitch 136
    __shared__ __align__(16) _Float16 s_j[64*72];       // [v][o] pitch 72
    __shared__ float s_w3d[64];

    const int tid  = threadIdx.x;
    const int lane = tid & 63;
    const int wv   = tid >> 6;
    const int v0   = blockIdx.x * 64;
    const int r    = lane & 15;
    const int kh   = lane >> 4;
    const int vsv  = tid >> 2;
    const int q_   = tid & 3;

    // ---- issue vf + w3d + coords loads ----
    float4 vfr[4];
    {
        const float4* src = (const float4*)(vf + (size_t)(v0 + vsv)*C3D_ + q_*16);
        #pragma unroll
        for (int i = 0; i < 4; ++i) vfr[i] = src[i];
    }
    const float w3 = w3d_buf[v0 + vsv];
    const int4 cc = ((const int4*)coords)[v0 + vsv];

    // ---- per-thread gather meta ----
    int ga[4]; float gw[4];
    {
        const int vb = cc.x;
        const float crx = cc.w * 0.05f;
        const float cry = cc.z * 0.05f - 40.0f;
        const float px = (crx + 0.025f) * 10.f + 156.f;
        const float py = (cry + 0.025f) * 10.f + 48.f;
        const float nx = fminf(fmaxf(px / 312.f * 2.f - 1.f, -1.f), 1.f);
        const float ny = fminf(fmaxf(py / 96.f  * 2.f - 1.f, -1.f), 1.f);
        const float fx = ((nx + 1.f) * 312.f - 1.f) * 0.5f;
        const float fy = ((ny + 1.f) * 96.f  - 1.f) * 0.5f;
        const float x0f = floorf(fx), y0f = floorf(fy);
        const float wx1 = fx - x0f, wy1 = fy - y0f;
        const int x0 = (int)x0f, y0 = (int)y0f;
        #pragma unroll
        for (int c = 0; c < 4; ++c) {
            int xi = x0 + (c & 1), yi = y0 + (c >> 1);
            bool valid = (xi >= 0) && (xi < IW) && (yi >= 0) && (yi < IH);
            int xc = min(max(xi, 0), IW - 1);
            int yc = min(max(yi, 0), IH - 1);
            ga[c] = ((vb*IH + yc)*IW + xc) * OUTC;
            float wx = (c & 1) ? wx1 : 1.f - wx1;
            float wy = (c >> 1) ? wy1 : 1.f - wy1;
            gw[c] = valid ? wx * wy : 0.f;
        }
    }

    // ---- issue J-gather early (drains at bar1 concurrently with vfr) ----
    half8 jreg[4][2];
    #pragma unroll
    for (int c = 0; c < 4; ++c)
        #pragma unroll
        for (int h = 0; h < 2; ++h)
            jreg[c][h] = *(const half8*)&Jimg[ga[c] + (h*4 + q_)*8];

    // ---- weight fragments + biases (L2-hot) ----
    half8 bvt[2][2];
    float sbvt[2];
    #pragma unroll
    for (int nt = 0; nt < 2; ++nt) {
        int o = (2*wv + nt)*16 + r;
        #pragma unroll
        for (int ks = 0; ks < 2; ++ks)
            bvt[nt][ks] = *(const half8*)&w_vt_s[o*C3D_ + ks*32 + kh*8];
        sbvt[nt] = sb_vt[o];
    }
    const int of = wv*16 + r;
    half8 bf1[4];
    #pragma unroll
    for (int ks = 0; ks < 4; ++ks)
        bf1[ks] = *(const half8*)&w_f1_s[of*128 + ks*32 + kh*8];
    const float sbf = sb_f[of];

    // ---- stage vf -> fp16 LDS; publish w3d ----
    #pragma unroll
    for (int i = 0; i < 4; ++i) {
        float4 x = vfr[i];
        half4v h;
        h[0] = (_Float16)x.x; h[1] = (_Float16)x.y;
        h[2] = (_Float16)x.z; h[3] = (_Float16)x.w;
        *(half4v*)&s_vf[vsv*72 + q_*16 + i*4] = h;
    }
    if (q_ == 0) s_w3d[vsv] = w3;
    __syncthreads();

    // ---- phase 1a: vt = relu(vf @ w_vt_s^T + sb) * w3d -> s_fused ----
    #pragma unroll
    for (int mt = 0; mt < 4; ++mt) {
        f32x4 a0 = {0.f,0.f,0.f,0.f}, a1 = {0.f,0.f,0.f,0.f};
        #pragma unroll
        for (int ks = 0; ks < 2; ++ks) {
            half8 af = *(const half8*)&s_vf[(mt*16 + r)*72 + ks*32 + kh*8];
            a0 = MFMA16(af, bvt[0][ks], a0);
            a1 = MFMA16(af, bvt[1][ks], a1);
        }
        #pragma unroll
        for (int rr = 0; rr < 4; ++rr) {
            int v = mt*16 + kh*4 + rr;
            float w3v = s_w3d[v];
            s_fused[v*136 + (2*wv+0)*16 + r] =
                (_Float16)(fmaxf(a0[rr] + sbvt[0], 0.f) * w3v);
            s_fused[v*136 + (2*wv+1)*16 + r] =
                (_Float16)(fmaxf(a1[rr] + sbvt[1], 0.f) * w3v);
        }
    }

    // ---- gather combine: (1-w3d)*sum_c gw[c]*J_c -> s_j ----
    {
        float invw = 1.f - w3;
        #pragma unroll
        for (int h = 0; h < 2; ++h) {
            half8 res;
            #pragma unroll
            for (int i = 0; i < 8; ++i) {
                float s = gw[0]*(float)jreg[0][h][i] + gw[1]*(float)jreg[1][h][i]
                        + gw[2]*(float)jreg[2][h][i] + gw[3]*(float)jreg[3][h][i];
                res[i] = (_Float16)(s * invw);
            }
            *(half8*)&s_j[vsv*72 + (h*4 + q_)*8] = res;
        }
    }
    __syncthreads();

    // ---- phase 2: out = relu(fused @ w_f1_s^T + j + sb_f) ----
    #pragma unroll
    for (int mt = 0; mt < 4; ++mt) {
        f32x4 acc = {0.f,0.f,0.f,0.f};
        #pragma unroll
        for (int ks = 0; ks < 4; ++ks) {
            half8 af = *(const half8*)&s_fused[(mt*16 + r)*136 + ks*32 + kh*8];
            acc = MFMA16(af, bf1[ks], acc);
        }
        #pragma unroll
        for (int rr = 0; rr < 4; ++rr) {
            int v = mt*16 + kh*4 + rr;
            float jv = (float)s_j[v*72 + of];
            out[(size_t)(v0 + v)*OUTC + of] = fmaxf(acc[rr] + jv + sbf, 0.f);
        }
    }
}

// ---------------------------------------------------------------------------
extern "C" void kernel_launch(void* const* d_in, const int* in_sizes, int n_in,
                              void* d_out, int out_size, void* d_ws, size_t ws_size,
                              hipStream_t stream)
{
    const float* vf    = (const float*)d_in[0];
    const int*   vc    = (const int*)  d_in[1];
    const float* img   = (const float*)d_in[2];
    const float* gtb   = (const float*)d_in[3];
    const int*   gtc   = (const int*)  d_in[4];
    const float* w_vt  = (const float*)d_in[5];
    const float* b_vt  = (const float*)d_in[6];
    const float* g_vt  = (const float*)d_in[7];
    const float* be_vt = (const float*)d_in[8];
    const float* m_vt  = (const float*)d_in[9];
    const float* v_vt  = (const float*)d_in[10];
    const float* w_it  = (const float*)d_in[11];
    const float* b_it  = (const float*)d_in[12];
    const float* g_it  = (const float*)d_in[13];
    const float* be_it = (const float*)d_in[14];
    const float* m_it  = (const float*)d_in[15];
    const float* v_it  = (const float*)d_in[16];
    const float* w_f   = (const float*)d_in[17];
    const float* b_f   = (const float*)d_in[18];
    const float* g_f   = (const float*)d_in[19];
    const float* be_f  = (const float*)d_in[20];
    const float* m_f   = (const float*)d_in[21];
    const float* v_f   = (const float*)d_in[22];

    _Float16* ws_h   = (_Float16*)d_ws;
    _Float16* Jbuf   = ws_h;                              // B*IHW*64 halves
    _Float16* w_vt_s = ws_h + (size_t)BATCH*IHW*OUTC;     // 8192
    _Float16* w_it_s = w_vt_s + MIDC*C3D_;                // 32768
    _Float16* w_f1_s = w_it_s + MIDC*C2D_;                // 8192
    _Float16* w_f2_s = w_f1_s + OUTC*128;                 // 8192
    float*    fbase  = (float*)(w_f2_s + OUTC*128);
    float* sb_vt   = fbase;                               // 128
    float* sb_it   = sb_vt + MIDC;                        // 128
    float* sb_f    = sb_it + MIDC;                        // 64
    float* w3d_buf = sb_f + OUTC;                         // N_VOX
    float* outp = (float*)d_out;

    prep_all<<<N_VOX/256, 256, 0, stream>>>(
        vc, gtb, gtc,
        w_vt, g_vt, v_vt, b_vt, be_vt, m_vt,
        w_it, g_it, v_it, b_it, be_it, m_it,
        w_f,  g_f,  v_f,  b_f,  be_f,  m_f,
        w_vt_s, w_it_s, w_f1_s, w_f2_s,
        sb_vt, sb_it, sb_f, w3d_buf);

    img_transform<<<dim3(IHW/64, BATCH), 256, 0, stream>>>(
        img, w_it_s, w_f2_s, sb_it, Jbuf);

    voxel_fuse<<<N_VOX/64, 256, 0, stream>>>(
        vf, vc, w_vt_s, sb_vt, Jbuf, w_f1_s, sb_f, w3d_buf, outp);
}